// Round 3
// baseline (428.076 us; speedup 1.0000x reference)
//
#include <hip/hip_runtime.h>

// ---------- types / helpers ----------
typedef __attribute__((ext_vector_type(8)))  short short8;   // 8 bf16 = 4 VGPRs
typedef __attribute__((ext_vector_type(16))) float f32x16;   // 32x32 MFMA acc

__device__ __forceinline__ float bf2f(unsigned short u) {
    union { unsigned int i; float f; } x; x.i = ((unsigned int)u) << 16; return x.f;
}
__device__ __forceinline__ unsigned short f2bf(float f) {
    union { float f; unsigned int i; } x; x.f = f;
    unsigned int r = x.i + 0x7fffu + ((x.i >> 16) & 1u);   // RTNE
    return (unsigned short)(r >> 16);
}
__device__ __forceinline__ void async_copy16(const void* g, void* l) {
    __builtin_amdgcn_global_load_lds(
        (const __attribute__((address_space(1))) void*)g,
        (__attribute__((address_space(3))) void*)l,
        16, 0, 0);
}

// ---------- fp32 -> bf16 convert (x) ----------
__global__ __launch_bounds__(256) void conv_f32_bf16(const float* __restrict__ in,
                                                     unsigned short* __restrict__ out, int n) {
    int i = (blockIdx.x * 256 + threadIdx.x) * 4;
    if (i < n) {
        float4 v = *(const float4*)&in[i];
        ushort4 o;
        o.x = f2bf(v.x); o.y = f2bf(v.y); o.z = f2bf(v.z); o.w = f2bf(v.w);
        *(ushort4*)&out[i] = o;
    }
}

// ---------- both weight transposes in one launch ----------
// Wqkv (1024x3072) -> WqkvT (3072x1024) for bx<96 ; Wout (1024x1024) -> WoutT else.
__global__ __launch_bounds__(256) void transpose_weights(const float* __restrict__ Wqkv,
                                                         unsigned short* __restrict__ WqkvT,
                                                         const float* __restrict__ Wout,
                                                         unsigned short* __restrict__ WoutT) {
    __shared__ float tile[32][33];
    const int R = 1024;
    const float* in; unsigned short* out; int C, bx;
    if (blockIdx.x < 96) { in = Wqkv; out = WqkvT; C = 3072; bx = blockIdx.x * 32; }
    else                 { in = Wout; out = WoutT; C = 1024; bx = (blockIdx.x - 96) * 32; }
    int by = blockIdx.y * 32;
    int tx = threadIdx.x & 31, ty = threadIdx.x >> 5;
    #pragma unroll
    for (int r = ty; r < 32; r += 8)
        tile[r][tx] = in[(size_t)(by + r) * C + bx + tx];
    __syncthreads();
    #pragma unroll
    for (int r = ty; r < 32; r += 8)
        out[(size_t)(bx + r) * R + by + tx] = f2bf(tile[tx][r]);
}

// ---------- bf16 GEMM: C[M,N] = A[M,K] * Bt[N,K]^T + bias ----------
// BM=BN=128, BK=64, 256 threads (4 waves 2x2), wave = 64x64 via 2x2 MFMA 32x32x16.
// LDS 16B chunks XOR-swizzled (pos = chunk ^ (row&7)) -> conflict-free ds_read_b128.
template<bool OUT_BF16>
__global__ __launch_bounds__(256) void gemm_bf16(const unsigned short* __restrict__ A, int lda,
                                                 const unsigned short* __restrict__ Bt, int ldb,
                                                 const float* __restrict__ bias,
                                                 void* __restrict__ C, int ldc, int K) {
    __shared__ short smem[16384];          // 32768 B: As[128][64] | Bs[128][64]
    short* As = smem;
    short* Bs = smem + 8192;

    const int tid    = threadIdx.x;
    const int lane   = tid & 63;
    const int wid    = tid >> 6;
    const int wave_m = wid >> 1, wave_n = wid & 1;
    const int half   = lane >> 5;          // 0/1
    const int l32    = lane & 31;
    const int m0     = blockIdx.x * 128;
    const int n0     = blockIdx.y * 128;

    // hoisted staging offsets (lane-invariant across K-loop)
    size_t aoff[4], boff[4];
    int ldst[4];
    #pragma unroll
    for (int j = 0; j < 4; j++) {
        const int L = j * 256 + tid;
        const int r = L >> 3;
        const int c = ((L & 7) ^ (r & 7)) * 8;     // swizzled source chunk
        aoff[j] = (size_t)(m0 + r) * lda + c;
        boff[j] = (size_t)(n0 + r) * ldb + c;
        ldst[j] = L * 8;
    }
    // hoisted fragment rows
    int rowA[2], rowB[2];
    #pragma unroll
    for (int i = 0; i < 2; i++) { rowA[i] = wave_m * 64 + i * 32 + l32;
                                  rowB[i] = wave_n * 64 + i * 32 + l32; }

    f32x16 acc[2][2] = {};

    for (int k0 = 0; k0 < K; k0 += 64) {
        __syncthreads();   // previous iter's LDS reads done
        #pragma unroll
        for (int j = 0; j < 4; j++) async_copy16(A  + aoff[j] + k0, &As[ldst[j]]);
        #pragma unroll
        for (int j = 0; j < 4; j++) async_copy16(Bt + boff[j] + k0, &Bs[ldst[j]]);
        __syncthreads();   // drain global_load_lds

        #pragma unroll
        for (int ks = 0; ks < 4; ks++) {
            const int sc = ks * 2 + half;          // source 8-short chunk index
            short8 af[2], bfr[2];
            #pragma unroll
            for (int i = 0; i < 2; i++)
                af[i]  = *(const short8*)&As[rowA[i] * 64 + (sc ^ (rowA[i] & 7)) * 8];
            #pragma unroll
            for (int j = 0; j < 2; j++)
                bfr[j] = *(const short8*)&Bs[rowB[j] * 64 + (sc ^ (rowB[j] & 7)) * 8];
            #pragma unroll
            for (int i = 0; i < 2; i++)
                #pragma unroll
                for (int j = 0; j < 2; j++)
                    acc[i][j] = __builtin_amdgcn_mfma_f32_32x32x16_bf16(af[i], bfr[j], acc[i][j], 0, 0, 0);
        }
    }

    // C/D layout (32x32): col = lane&31, row = (reg&3) + 8*(reg>>2) + 4*(lane>>5)  [m74/m101]
    if (OUT_BF16) {
        unsigned short* tile = (unsigned short*)smem;   // [64][136] padded, 17408 B
        unsigned short* Cp = (unsigned short*)C;
        #pragma unroll
        for (int p = 0; p < 2; p++) {                   // two 64-row passes
            __syncthreads();
            if (wave_m == p) {
                #pragma unroll
                for (int j = 0; j < 2; j++) {
                    const int col = wave_n * 64 + j * 32 + l32;
                    const float bv = bias[n0 + col];
                    #pragma unroll
                    for (int i = 0; i < 2; i++) {
                        const int rbase = i * 32 + 4 * half;
                        #pragma unroll
                        for (int r = 0; r < 16; r++) {
                            const int row = rbase + (r & 3) + 8 * (r >> 2);
                            tile[row * 136 + col] = f2bf(acc[i][j][r] + bv);
                        }
                    }
                }
            }
            __syncthreads();
            const int row = tid >> 2;                   // 64 rows, 4 threads/row
            const int col = (tid & 3) * 32;
            short8 v0 = *(const short8*)&tile[row * 136 + col];
            short8 v1 = *(const short8*)&tile[row * 136 + col + 8];
            short8 v2 = *(const short8*)&tile[row * 136 + col + 16];
            short8 v3 = *(const short8*)&tile[row * 136 + col + 24];
            unsigned short* dst = &Cp[(size_t)(m0 + p * 64 + row) * ldc + n0 + col];
            *(short8*)&dst[0]  = v0;
            *(short8*)&dst[8]  = v1;
            *(short8*)&dst[16] = v2;
            *(short8*)&dst[24] = v3;
        }
    } else {
        float* Cp = (float*)C;
        #pragma unroll
        for (int j = 0; j < 2; j++) {
            const int col = n0 + wave_n * 64 + j * 32 + l32;
            const float bv = bias[col];
            #pragma unroll
            for (int i = 0; i < 2; i++) {
                const int growb = m0 + wave_m * 64 + i * 32 + 4 * half;
                #pragma unroll
                for (int r = 0; r < 16; r++) {
                    const int grow = growb + (r & 3) + 8 * (r >> 2);
                    Cp[(size_t)grow * ldc + col] = acc[i][j][r] + bv;
                }
            }
        }
    }
}

// ---------- per-row q/k norms + kv pool ----------
// One wave per 4 rows; wave-shuffle reductions only. grid = 16384/16 = 1024 blocks.
__global__ __launch_bounds__(256) void norm_kv(const unsigned short* __restrict__ qkv,
                                               float* __restrict__ rnq,
                                               float* __restrict__ kv) {
    __shared__ float kvbuf[1024];
    const int tid = threadIdx.x, lane = tid & 63, wv = tid >> 6;
    *(float4*)&kvbuf[tid * 4] = make_float4(0.f, 0.f, 0.f, 0.f);
    __syncthreads();

    const int row0 = blockIdx.x * 16 + wv * 4;
    float a[4][4] = {};

    for (int rr = 0; rr < 4; rr++) {
        const size_t base = (size_t)(row0 + rr) * 3072;
        float q2 = 0.f;
        #pragma unroll
        for (int c = 0; c < 4; c++) {
            ushort4 qu = *(const ushort4*)&qkv[base + c * 256 + lane * 4];
            float x0 = bf2f(qu.x), x1 = bf2f(qu.y), x2 = bf2f(qu.z), x3 = bf2f(qu.w);
            q2 += x0 * x0 + x1 * x1 + x2 * x2 + x3 * x3;
        }
        #pragma unroll
        for (int m = 32; m; m >>= 1) q2 += __shfl_xor(q2, m, 64);
        if (lane == 0) rnq[row0 + rr] = rsqrtf(q2);

        float k2 = 0.f;
        float kf[4][4];
        #pragma unroll
        for (int c = 0; c < 4; c++) {
            ushort4 ku = *(const ushort4*)&qkv[base + 1024 + c * 256 + lane * 4];
            kf[c][0] = bf2f(ku.x); kf[c][1] = bf2f(ku.y);
            kf[c][2] = bf2f(ku.z); kf[c][3] = bf2f(ku.w);
            k2 += kf[c][0]*kf[c][0] + kf[c][1]*kf[c][1] + kf[c][2]*kf[c][2] + kf[c][3]*kf[c][3];
        }
        #pragma unroll
        for (int m = 32; m; m >>= 1) k2 += __shfl_xor(k2, m, 64);
        const float rk = rsqrtf(k2);

        #pragma unroll
        for (int c = 0; c < 4; c++) {
            ushort4 vu = *(const ushort4*)&qkv[base + 2048 + c * 256 + lane * 4];
            a[c][0] += kf[c][0] * rk * bf2f(vu.x);
            a[c][1] += kf[c][1] * rk * bf2f(vu.y);
            a[c][2] += kf[c][2] * rk * bf2f(vu.z);
            a[c][3] += kf[c][3] * rk * bf2f(vu.w);
        }
    }
    #pragma unroll
    for (int c = 0; c < 4; c++)
        #pragma unroll
        for (int i = 0; i < 4; i++)
            atomicAdd(&kvbuf[c * 256 + lane * 4 + i], a[c][i]);
    __syncthreads();
    const int b = blockIdx.x >> 8;     // 256 blocks per batch (4096 rows / 16)
    #pragma unroll
    for (int i = 0; i < 4; i++)
        atomicAdd(&kv[b * 1024 + tid * 4 + i], kvbuf[tid * 4 + i]);
}

// ---------- out = q_hat * kv  (written into qkv's dead v-region, bf16) ----------
__global__ __launch_bounds__(256) void scale_q(unsigned short* __restrict__ qkv,
                                               const float* __restrict__ rnq,
                                               const float* __restrict__ kv, int T) {
    const int t = blockIdx.x;
    const int b = t / T;
    const int d = threadIdx.x * 4;
    const float rq = rnq[t];
    const size_t base = (size_t)t * 3072;
    ushort4 qu = *(const ushort4*)&qkv[base + d];
    float4 kvv = *(const float4*)&kv[b * 1024 + d];
    ushort4 o;
    o.x = f2bf(bf2f(qu.x) * rq * kvv.x);
    o.y = f2bf(bf2f(qu.y) * rq * kvv.y);
    o.z = f2bf(bf2f(qu.z) * rq * kvv.z);
    o.w = f2bf(bf2f(qu.w) * rq * kvv.w);
    *(ushort4*)&qkv[base + 2048 + d] = o;
}

extern "C" void kernel_launch(void* const* d_in, const int* in_sizes, int n_in,
                              void* d_out, int out_size, void* d_ws, size_t ws_size,
                              hipStream_t stream) {
    const float* x    = (const float*)d_in[0];   // (4,4096,1024)
    const float* Wqkv = (const float*)d_in[1];   // (1024,3072)
    const float* bqkv = (const float*)d_in[2];   // (3072)
    const float* Wout = (const float*)d_in[3];   // (1024,1024)
    const float* bout = (const float*)d_in[4];   // (1024)
    float* out = (float*)d_out;                  // (4,4096,1024) fp32

    char* ws = (char*)d_ws;
    unsigned short* x_bf  = (unsigned short*)(ws + 0);           // 32 MB
    unsigned short* WqkvT = (unsigned short*)(ws + 33554432);    // 6 MB
    unsigned short* WoutT = (unsigned short*)(ws + 39845888);    // 2 MB
    unsigned short* qkv   = (unsigned short*)(ws + 41943040);    // 96 MB
    float* rnq            = (float*)(ws + 142606336);            // 64 KB
    float* kv             = (float*)(ws + 142671872);            // 16 KB

    conv_f32_bf16<<<16384, 256, 0, stream>>>(x, x_bf, 16777216);
    transpose_weights<<<dim3(128, 32), 256, 0, stream>>>(Wqkv, WqkvT, Wout, WoutT);

    // qkv = x @ Wqkv + bqkv   (M=16384, N=3072, K=1024) -> bf16
    gemm_bf16<true><<<dim3(128, 24), 256, 0, stream>>>(x_bf, 1024, WqkvT, 1024, bqkv,
                                                       (void*)qkv, 3072, 1024);

    hipMemsetAsync(kv, 0, 4096 * sizeof(float), stream);
    norm_kv<<<1024, 256, 0, stream>>>(qkv, rnq, kv);

    scale_q<<<16384, 256, 0, stream>>>(qkv, rnq, kv, 4096);

    // y = out @ Wout + bout   (M=16384, N=1024, K=1024) -> fp32 d_out
    gemm_bf16<false><<<dim3(128, 8), 256, 0, stream>>>(qkv + 2048, 3072, WoutT, 1024, bout,
                                                       (void*)out, 1024, 1024);
}

// Round 4
// 388.114 us; speedup vs baseline: 1.1030x; 1.1030x over previous
//
#include <hip/hip_runtime.h>

// ---------- types / helpers ----------
typedef __attribute__((ext_vector_type(8))) short short8;   // 8 bf16 = 4 VGPRs
typedef __attribute__((ext_vector_type(4))) float f32x4;

__device__ __forceinline__ float bf2f(unsigned short u) {
    union { unsigned int i; float f; } x; x.i = ((unsigned int)u) << 16; return x.f;
}
__device__ __forceinline__ unsigned short f2bf(float f) {
    union { float f; unsigned int i; } x; x.f = f;
    unsigned int r = x.i + 0x7fffu + ((x.i >> 16) & 1u);   // RTNE
    return (unsigned short)(r >> 16);
}
__device__ __forceinline__ void async_copy16(const void* g, void* l) {
    __builtin_amdgcn_global_load_lds(
        (const __attribute__((address_space(1))) void*)g,
        (__attribute__((address_space(3))) void*)l,
        16, 0, 0);
}

// ---------- fp32 -> bf16 convert (x) + kv zero-init fold ----------
__global__ __launch_bounds__(256) void conv_f32_bf16(const float* __restrict__ in,
                                                     unsigned short* __restrict__ out,
                                                     float* __restrict__ kv) {
    if (blockIdx.x == 0) {          // zero kv[4096] (re-poisoned to 0xAA each call)
        #pragma unroll
        for (int c = 0; c < 4; c++)
            *(float4*)&kv[(threadIdx.x + c * 256) * 4] = make_float4(0.f, 0.f, 0.f, 0.f);
    }
    int i = (blockIdx.x * 256 + threadIdx.x) * 8;
    float4 v0 = *(const float4*)&in[i];
    float4 v1 = *(const float4*)&in[i + 4];
    ushort4 o0, o1;
    o0.x = f2bf(v0.x); o0.y = f2bf(v0.y); o0.z = f2bf(v0.z); o0.w = f2bf(v0.w);
    o1.x = f2bf(v1.x); o1.y = f2bf(v1.y); o1.z = f2bf(v1.z); o1.w = f2bf(v1.w);
    *(ushort4*)&out[i]     = o0;
    *(ushort4*)&out[i + 4] = o1;
}

// ---------- both weight transposes in one launch ----------
__global__ __launch_bounds__(256) void transpose_weights(const float* __restrict__ Wqkv,
                                                         unsigned short* __restrict__ WqkvT,
                                                         const float* __restrict__ Wout,
                                                         unsigned short* __restrict__ WoutT) {
    __shared__ float tile[32][33];
    const int R = 1024;
    const float* in; unsigned short* out; int C, bx;
    if (blockIdx.x < 96) { in = Wqkv; out = WqkvT; C = 3072; bx = blockIdx.x * 32; }
    else                 { in = Wout; out = WoutT; C = 1024; bx = (blockIdx.x - 96) * 32; }
    int by = blockIdx.y * 32;
    int tx = threadIdx.x & 31, ty = threadIdx.x >> 5;
    #pragma unroll
    for (int r = ty; r < 32; r += 8)
        tile[r][tx] = in[(size_t)(by + r) * C + bx + tx];
    __syncthreads();
    #pragma unroll
    for (int r = ty; r < 32; r += 8)
        out[(size_t)(bx + r) * R + by + tx] = f2bf(tile[tx][r]);
}

// ---------- bf16 GEMM: C[M,N] = A[M,K] * Bt[N,K]^T (+bias, opt. row-scale) ----------
// BM=BN=128, BK=64, 256 threads (4 waves 2x2), wave = 64x64 via 4x4 MFMA 16x16x32.
// Round-2 proven config: quad-based XOR chunk swizzle -> conflict-free ds_read_b128.
// MODE 0: bf16 out, +bias.  MODE 1: fp32 out, acc*rnq[row] + bias, Bt batched by m-tile.
template<int MODE>
__global__ __launch_bounds__(256) void gemm_bf16(const unsigned short* __restrict__ A, int lda,
                                                 const unsigned short* __restrict__ Bt, int ldb,
                                                 const float* __restrict__ bias,
                                                 const float* __restrict__ rnq,
                                                 void* __restrict__ C, int ldc, int K) {
    __shared__ short smem[17408];          // K-loop: As[128][64] | Bs[128][64]; epi: tile[128][136]
    short* As = smem;
    short* Bs = smem + 8192;

    const int tid    = threadIdx.x;
    const int lane   = tid & 63;
    const int wid    = tid >> 6;
    const int wave_m = wid >> 1, wave_n = wid & 1;
    const int quad   = lane >> 4;
    const int l16    = lane & 15;
    const int m0     = blockIdx.x * 128;
    const int n0     = blockIdx.y * 128;

    if (MODE == 1) Bt += (size_t)(blockIdx.x >> 5) * 1048576;   // batch b = m0/4096

    // hoisted staging offsets (K-loop-invariant)
    size_t aoff[4], boff[4];
    int ldst[4];
    #pragma unroll
    for (int j = 0; j < 4; j++) {
        const int L = j * 256 + tid;
        const int r = L >> 3;
        const int c = ((L & 7) ^ (r & 7)) * 8;     // swizzled source chunk
        aoff[j] = (size_t)(m0 + r) * lda + c;
        boff[j] = (size_t)(n0 + r) * ldb + c;
        ldst[j] = L * 8;
    }
    // hoisted fragment row offsets
    int rA[4], rB[4];
    #pragma unroll
    for (int i = 0; i < 4; i++) { rA[i] = wave_m * 64 + i * 16 + l16;
                                  rB[i] = wave_n * 64 + i * 16 + l16; }

    f32x4 acc[4][4] = {};

    for (int k0 = 0; k0 < K; k0 += 64) {
        __syncthreads();   // previous iter's LDS reads done
        #pragma unroll
        for (int j = 0; j < 4; j++) async_copy16(A  + aoff[j] + k0, &As[ldst[j]]);
        #pragma unroll
        for (int j = 0; j < 4; j++) async_copy16(Bt + boff[j] + k0, &Bs[ldst[j]]);
        __syncthreads();   // drain global_load_lds

        #pragma unroll
        for (int kk = 0; kk < 2; kk++) {
            short8 af[4], bfr[4];
            #pragma unroll
            for (int i = 0; i < 4; i++)
                af[i]  = *(const short8*)&As[rA[i] * 64 + (((quad + kk * 4) ^ (rA[i] & 7)) * 8)];
            #pragma unroll
            for (int j = 0; j < 4; j++)
                bfr[j] = *(const short8*)&Bs[rB[j] * 64 + (((quad + kk * 4) ^ (rB[j] & 7)) * 8)];
            #pragma unroll
            for (int i = 0; i < 4; i++)
                #pragma unroll
                for (int j = 0; j < 4; j++)
                    acc[i][j] = __builtin_amdgcn_mfma_f32_16x16x32_bf16(af[i], bfr[j], acc[i][j], 0, 0, 0);
        }
    }

    // C/D layout: col = lane&15, row = quad*4 + r   [m89/m91]
    if (MODE == 0) {
        __syncthreads();
        unsigned short* tile = (unsigned short*)smem;   // [128][136] padded
        #pragma unroll
        for (int j = 0; j < 4; j++) {
            const int tcol = wave_n * 64 + j * 16 + l16;
            const float bv = bias[n0 + tcol];
            #pragma unroll
            for (int i = 0; i < 4; i++) {
                const int trow = wave_m * 64 + i * 16 + quad * 4;
                #pragma unroll
                for (int r = 0; r < 4; r++)
                    tile[(trow + r) * 136 + tcol] = f2bf(acc[i][j][r] + bv);
            }
        }
        __syncthreads();
        unsigned short* Cp = (unsigned short*)C;
        #pragma unroll
        for (int p = 0; p < 4; p++) {
            const int row = p * 32 + (tid >> 3);
            const int col = (tid & 7) * 16;
            short8 v0 = *(const short8*)&tile[row * 136 + col];
            short8 v1 = *(const short8*)&tile[row * 136 + col + 8];
            *(short8*)&Cp[(size_t)(m0 + row) * ldc + n0 + col]     = v0;
            *(short8*)&Cp[(size_t)(m0 + row) * ldc + n0 + col + 8] = v1;
        }
    } else {
        float* Cp = (float*)C;
        #pragma unroll
        for (int i = 0; i < 4; i++) {
            const int growb = m0 + wave_m * 64 + i * 16 + quad * 4;
            const float4 rq4 = *(const float4*)&rnq[growb];     // 4 contiguous rows
            #pragma unroll
            for (int j = 0; j < 4; j++) {
                const int gcol = n0 + wave_n * 64 + j * 16 + l16;
                const float bv = bias[gcol];
                Cp[(size_t)(growb + 0) * ldc + gcol] = acc[i][j][0] * rq4.x + bv;
                Cp[(size_t)(growb + 1) * ldc + gcol] = acc[i][j][1] * rq4.y + bv;
                Cp[(size_t)(growb + 2) * ldc + gcol] = acc[i][j][2] * rq4.z + bv;
                Cp[(size_t)(growb + 3) * ldc + gcol] = acc[i][j][3] * rq4.w + bv;
            }
        }
    }
}

// ---------- per-row q/k norms + kv pool ----------
// One wave per 4 rows; wave-shuffle reductions only. grid = 1024 blocks.
__global__ __launch_bounds__(256) void norm_kv(const unsigned short* __restrict__ qkv,
                                               float* __restrict__ rnq,
                                               float* __restrict__ kv) {
    __shared__ float kvbuf[1024];
    const int tid = threadIdx.x, lane = tid & 63, wv = tid >> 6;
    *(float4*)&kvbuf[tid * 4] = make_float4(0.f, 0.f, 0.f, 0.f);
    __syncthreads();

    const int row0 = blockIdx.x * 16 + wv * 4;
    float a[4][4] = {};

    for (int rr = 0; rr < 4; rr++) {
        const size_t base = (size_t)(row0 + rr) * 3072;
        float q2 = 0.f;
        #pragma unroll
        for (int c = 0; c < 4; c++) {
            ushort4 qu = *(const ushort4*)&qkv[base + c * 256 + lane * 4];
            float x0 = bf2f(qu.x), x1 = bf2f(qu.y), x2 = bf2f(qu.z), x3 = bf2f(qu.w);
            q2 += x0 * x0 + x1 * x1 + x2 * x2 + x3 * x3;
        }
        #pragma unroll
        for (int m = 32; m; m >>= 1) q2 += __shfl_xor(q2, m, 64);
        if (lane == 0) rnq[row0 + rr] = rsqrtf(q2);

        float k2 = 0.f;
        float kf[4][4];
        #pragma unroll
        for (int c = 0; c < 4; c++) {
            ushort4 ku = *(const ushort4*)&qkv[base + 1024 + c * 256 + lane * 4];
            kf[c][0] = bf2f(ku.x); kf[c][1] = bf2f(ku.y);
            kf[c][2] = bf2f(ku.z); kf[c][3] = bf2f(ku.w);
            k2 += kf[c][0]*kf[c][0] + kf[c][1]*kf[c][1] + kf[c][2]*kf[c][2] + kf[c][3]*kf[c][3];
        }
        #pragma unroll
        for (int m = 32; m; m >>= 1) k2 += __shfl_xor(k2, m, 64);
        const float rk = rsqrtf(k2);

        #pragma unroll
        for (int c = 0; c < 4; c++) {
            ushort4 vu = *(const ushort4*)&qkv[base + 2048 + c * 256 + lane * 4];
            a[c][0] += kf[c][0] * rk * bf2f(vu.x);
            a[c][1] += kf[c][1] * rk * bf2f(vu.y);
            a[c][2] += kf[c][2] * rk * bf2f(vu.z);
            a[c][3] += kf[c][3] * rk * bf2f(vu.w);
        }
    }
    #pragma unroll
    for (int c = 0; c < 4; c++)
        #pragma unroll
        for (int i = 0; i < 4; i++)
            atomicAdd(&kvbuf[c * 256 + lane * 4 + i], a[c][i]);
    __syncthreads();
    const int b = blockIdx.x >> 8;     // 256 blocks per batch
    #pragma unroll
    for (int i = 0; i < 4; i++)
        atomicAdd(&kv[b * 1024 + tid * 4 + i], kvbuf[tid * 4 + i]);
}

// ---------- W'_b^T[n][k] = WoutT[n][k] * kv[b][k]  (bf16) ----------
__global__ __launch_bounds__(256) void wprep(const unsigned short* __restrict__ WoutT,
                                             const float* __restrict__ kv,
                                             unsigned short* __restrict__ WbT) {
    const int b = blockIdx.x >> 10, n = blockIdx.x & 1023, k = threadIdx.x * 4;
    ushort4 w = *(const ushort4*)&WoutT[n * 1024 + k];
    float4 kvv = *(const float4*)&kv[b * 1024 + k];
    ushort4 o;
    o.x = f2bf(bf2f(w.x) * kvv.x);
    o.y = f2bf(bf2f(w.y) * kvv.y);
    o.z = f2bf(bf2f(w.z) * kvv.z);
    o.w = f2bf(bf2f(w.w) * kvv.w);
    *(ushort4*)&WbT[((size_t)b << 20) + n * 1024 + k] = o;
}

extern "C" void kernel_launch(void* const* d_in, const int* in_sizes, int n_in,
                              void* d_out, int out_size, void* d_ws, size_t ws_size,
                              hipStream_t stream) {
    const float* x    = (const float*)d_in[0];   // (4,4096,1024)
    const float* Wqkv = (const float*)d_in[1];   // (1024,3072)
    const float* bqkv = (const float*)d_in[2];   // (3072)
    const float* Wout = (const float*)d_in[3];   // (1024,1024)
    const float* bout = (const float*)d_in[4];   // (1024)
    float* out = (float*)d_out;                  // (4,4096,1024) fp32

    char* ws = (char*)d_ws;
    unsigned short* x_bf  = (unsigned short*)(ws + 0);           // 32 MB; dead after GEMM1
    unsigned short* WbT   = x_bf;                                // 8 MB, reuses x_bf region
    unsigned short* WqkvT = (unsigned short*)(ws + 33554432);    // 6 MB
    unsigned short* WoutT = (unsigned short*)(ws + 39845888);    // 2 MB
    unsigned short* qkv   = (unsigned short*)(ws + 41943040);    // 96 MB
    float* rnq            = (float*)(ws + 142606336);            // 64 KB
    float* kv             = (float*)(ws + 142671872);            // 16 KB

    conv_f32_bf16<<<8192, 256, 0, stream>>>(x, x_bf, kv);
    transpose_weights<<<dim3(128, 32), 256, 0, stream>>>(Wqkv, WqkvT, Wout, WoutT);

    // qkv = x @ Wqkv + bqkv   (M=16384, N=3072, K=1024) -> bf16
    gemm_bf16<0><<<dim3(128, 24), 256, 0, stream>>>(x_bf, 1024, WqkvT, 1024, bqkv, nullptr,
                                                    (void*)qkv, 3072, 1024);

    norm_kv<<<1024, 256, 0, stream>>>(qkv, rnq, kv);
    wprep<<<4096, 256, 0, stream>>>(WoutT, kv, WbT);

    // y = rnq .* (q @ W'_b) + bout   (M=16384, N=1024, K=1024) -> fp32 d_out
    gemm_bf16<1><<<dim3(128, 8), 256, 0, stream>>>(qkv, 3072, WbT, 1024, bout, rnq,
                                                   (void*)out, 1024, 1024);
}